// Round 1
// baseline (4201.841 us; speedup 1.0000x reference)
//
#include <hip/hip_runtime.h>

#define C_   15
#define H_   256
#define O_   512
#define T_   60
#define B_   1024
#define G3H_ (3*H_)
#define MAXT 80   // sum ceil(Bc/16) <= (1024 + 15*15)/16 = 78

__device__ __forceinline__ float sigmoidf_(float x) { return 1.f / (1.f + __expf(-x)); }
__device__ __forceinline__ float tanhf_(float x)    { return 2.f * sigmoidf_(2.f * x) - 1.f; }

// ---------------- sort: group samples by camera, build 16-row tiles ----------------
__global__ __launch_bounds__(256) void sort_kernel(const int* __restrict__ cam,
    int* __restrict__ order, int* __restrict__ tcam, int* __restrict__ toff,
    int* __restrict__ tcnt)
{
    __shared__ int cnt[C_], start[C_], fill[C_];
    int tid = threadIdx.x;
    if (tid < C_) cnt[tid] = 0;
    __syncthreads();
    for (int b = tid; b < B_; b += 256) atomicAdd(&cnt[cam[b]], 1);
    __syncthreads();
    if (tid == 0) {
        int run = 0;
        for (int c = 0; c < C_; ++c) { start[c] = run; fill[c] = run; run += cnt[c]; }
    }
    __syncthreads();
    for (int b = tid; b < B_; b += 256) {
        int pos = atomicAdd(&fill[cam[b]], 1);
        order[pos] = b;
    }
    __syncthreads();
    if (tid == 0) {
        int ti = 0;
        for (int c = 0; c < C_; ++c) {
            for (int r = 0; r < cnt[c]; r += 16) {
                tcam[ti] = c; toff[ti] = start[c] + r;
                tcnt[ti] = min(16, cnt[c] - r); ++ti;
            }
        }
        for (; ti < MAXT; ++ti) { tcam[ti] = -1; toff[ti] = 0; tcnt[ti] = 0; }
    }
}

// ---------------- gi = x*Wih^T + b_ih + b_hh(r,z only; NOT n) ----------------
__global__ __launch_bounds__(256) void gi_kernel(
    const float* __restrict__ x, const float* __restrict__ Wih,
    const float* __restrict__ bih, const float* __restrict__ bhh,
    const int* __restrict__ order, const int* __restrict__ tcam,
    const int* __restrict__ toff, const int* __restrict__ tcnt,
    float* __restrict__ gi)
{
    int bx = blockIdx.x;
    int c = tcam[bx]; if (c < 0) return;
    int cnt = tcnt[bx], off = toff[bx];
    int tid = threadIdx.x, lane = tid & 63, wv = tid >> 6;
    __shared__ float xt[16][H_];
    for (int m = wv; m < 16; m += 4) {
        float4 v = make_float4(0.f, 0.f, 0.f, 0.f);
        if (m < cnt) v = *(const float4*)&x[(size_t)order[off + m] * H_ + (lane << 2)];
        *(float4*)&xt[m][lane << 2] = v;
    }
    __syncthreads();
    int jj = blockIdx.y * 64 + lane;                    // h-column 0..255
    const float* wb = Wih + (size_t)c * G3H_ * H_;
    const float4* wr = (const float4*)(wb + (size_t)(jj) * H_);
    const float4* wz = (const float4*)(wb + (size_t)(H_ + jj) * H_);
    const float4* wn = (const float4*)(wb + (size_t)(2 * H_ + jj) * H_);
    float ar[4] = {0,0,0,0}, az[4] = {0,0,0,0}, an[4] = {0,0,0,0};
    for (int k4 = 0; k4 < H_ / 4; ++k4) {
        float4 a = wr[k4], b = wz[k4], d = wn[k4];
#pragma unroll
        for (int i = 0; i < 4; ++i) {
            float4 hv = *(const float4*)&xt[wv * 4 + i][k4 << 2];
            ar[i] = fmaf(a.w, hv.w, fmaf(a.z, hv.z, fmaf(a.y, hv.y, fmaf(a.x, hv.x, ar[i]))));
            az[i] = fmaf(b.w, hv.w, fmaf(b.z, hv.z, fmaf(b.y, hv.y, fmaf(b.x, hv.x, az[i]))));
            an[i] = fmaf(d.w, hv.w, fmaf(d.z, hv.z, fmaf(d.y, hv.y, fmaf(d.x, hv.x, an[i]))));
        }
    }
    float br = bih[c * G3H_ + jj] + bhh[c * G3H_ + jj];
    float bz = bih[c * G3H_ + H_ + jj] + bhh[c * G3H_ + H_ + jj];
    float bn = bih[c * G3H_ + 2 * H_ + jj];             // b_hh_n stays inside r*(...)
#pragma unroll
    for (int i = 0; i < 4; ++i) {
        int m = wv * 4 + i;
        if (m < cnt) {
            int b = order[off + m];
            gi[(size_t)b * G3H_ + jj]          = ar[i] + br;
            gi[(size_t)b * G3H_ + H_ + jj]     = az[i] + bz;
            gi[(size_t)b * G3H_ + 2 * H_ + jj] = an[i] + bn;
        }
    }
}

// ---------------- out role: out[:,oslice*256:+256,t] = sigmoid(h*Wc^T + bc) ----------------
__device__ __forceinline__ void out_role(
    const float* __restrict__ Wc, const float* __restrict__ bc,
    const int* __restrict__ order, int c, int off, int cnt,
    const float (*h_tile)[H_], int lane, int wv, int oslice, int t,
    float* __restrict__ outp)
{
    const float4* w0 = (const float4*)&Wc[((size_t)c * O_ + oslice * 256 + lane) * H_];
    const size_t rowstride = (size_t)64 * (H_ / 4);     // 64 rows, in float4 units
    float acc[4][4];
#pragma unroll
    for (int u = 0; u < 4; ++u)
#pragma unroll
        for (int i = 0; i < 4; ++i) acc[u][i] = 0.f;
    for (int k4 = 0; k4 < H_ / 4; ++k4) {
        float4 w[4];
#pragma unroll
        for (int u = 0; u < 4; ++u) w[u] = w0[u * rowstride + k4];
#pragma unroll
        for (int i = 0; i < 4; ++i) {
            float4 hv = *(const float4*)&h_tile[wv * 4 + i][k4 << 2];
#pragma unroll
            for (int u = 0; u < 4; ++u)
                acc[u][i] = fmaf(w[u].w, hv.w, fmaf(w[u].z, hv.z,
                             fmaf(w[u].y, hv.y, fmaf(w[u].x, hv.x, acc[u][i]))));
        }
    }
#pragma unroll
    for (int i = 0; i < 4; ++i) {
        int m = wv * 4 + i;
        if (m < cnt) {
            int b = order[off + m];
#pragma unroll
            for (int u = 0; u < 4; ++u) {
                int o = oslice * 256 + lane + 64 * u;
                float v = sigmoidf_(acc[u][i] + bc[c * O_ + o]);
                outp[((size_t)b * O_ + o) * T_ + t] = v;
            }
        }
    }
}

// ---------------- fused step: y<4 -> gh+gate update; y>=4 -> out for t=s-1 ----------------
__global__ __launch_bounds__(256) void step_kernel(
    const float* __restrict__ Whh, const float* __restrict__ bhh,
    const float* __restrict__ gi, const float* __restrict__ Wc,
    const float* __restrict__ bc, const int* __restrict__ order,
    const int* __restrict__ tcam, const int* __restrict__ toff,
    const int* __restrict__ tcnt, const float* __restrict__ h_in,
    float* __restrict__ h_out, float* __restrict__ outp, int s)
{
    int role = blockIdx.y;
    if (role >= 4 && s == 0) return;                    // no out_{-1}
    int bx = blockIdx.x;
    int c = tcam[bx]; if (c < 0) return;
    int cnt = tcnt[bx], off = toff[bx];
    int tid = threadIdx.x, lane = tid & 63, wv = tid >> 6;
    __shared__ float h_tile[16][H_];                    // 16 KB
    for (int m = wv; m < 16; m += 4) {
        float4 v = make_float4(0.f, 0.f, 0.f, 0.f);
        if (m < cnt) v = *(const float4*)&h_in[(size_t)order[off + m] * H_ + (lane << 2)];
        *(float4*)&h_tile[m][lane << 2] = v;
    }
    __syncthreads();

    if (role < 4) {
        int jj = role * 64 + lane;                      // h column 0..255
        const float* wb = Whh + (size_t)c * G3H_ * H_;
        const float4* wr = (const float4*)(wb + (size_t)(jj) * H_);
        const float4* wz = (const float4*)(wb + (size_t)(H_ + jj) * H_);
        const float4* wn = (const float4*)(wb + (size_t)(2 * H_ + jj) * H_);
        float ar[4] = {0,0,0,0}, az[4] = {0,0,0,0}, an[4] = {0,0,0,0};
        for (int k4 = 0; k4 < H_ / 4; ++k4) {
            float4 a = wr[k4], b = wz[k4], d = wn[k4];
#pragma unroll
            for (int i = 0; i < 4; ++i) {
                float4 hv = *(const float4*)&h_tile[wv * 4 + i][k4 << 2];
                ar[i] = fmaf(a.w, hv.w, fmaf(a.z, hv.z, fmaf(a.y, hv.y, fmaf(a.x, hv.x, ar[i]))));
                az[i] = fmaf(b.w, hv.w, fmaf(b.z, hv.z, fmaf(b.y, hv.y, fmaf(b.x, hv.x, az[i]))));
                an[i] = fmaf(d.w, hv.w, fmaf(d.z, hv.z, fmaf(d.y, hv.y, fmaf(d.x, hv.x, an[i]))));
            }
        }
        float bhn = bhh[c * G3H_ + 2 * H_ + jj];
#pragma unroll
        for (int i = 0; i < 4; ++i) {
            int m = wv * 4 + i;
            if (m < cnt) {
                int b = order[off + m];
                const float* gib = gi + (size_t)b * G3H_;
                float rr = sigmoidf_(gib[jj] + ar[i]);
                float zz = sigmoidf_(gib[H_ + jj] + az[i]);
                float nn = tanhf_(gib[2 * H_ + jj] + rr * (an[i] + bhn));
                float hnew = (1.f - zz) * nn + zz * h_tile[m][jj];
                h_out[(size_t)b * H_ + jj] = hnew;
            }
        }
    } else {
        out_role(Wc, bc, order, c, off, cnt, h_tile, lane, wv, role - 4, s - 1, outp);
    }
}

// ---------------- final out for t = T-1 ----------------
__global__ __launch_bounds__(256) void outlast_kernel(
    const float* __restrict__ Wc, const float* __restrict__ bc,
    const int* __restrict__ order, const int* __restrict__ tcam,
    const int* __restrict__ toff, const int* __restrict__ tcnt,
    const float* __restrict__ h_in, float* __restrict__ outp)
{
    int bx = blockIdx.x;
    int c = tcam[bx]; if (c < 0) return;
    int cnt = tcnt[bx], off = toff[bx];
    int tid = threadIdx.x, lane = tid & 63, wv = tid >> 6;
    __shared__ float h_tile[16][H_];
    for (int m = wv; m < 16; m += 4) {
        float4 v = make_float4(0.f, 0.f, 0.f, 0.f);
        if (m < cnt) v = *(const float4*)&h_in[(size_t)order[off + m] * H_ + (lane << 2)];
        *(float4*)&h_tile[m][lane << 2] = v;
    }
    __syncthreads();
    out_role(Wc, bc, order, c, off, cnt, h_tile, lane, wv, blockIdx.y, T_ - 1, outp);
}

extern "C" void kernel_launch(void* const* d_in, const int* in_sizes, int n_in,
                              void* d_out, int out_size, void* d_ws, size_t ws_size,
                              hipStream_t stream)
{
    const float* x   = (const float*)d_in[0];
    const int*   cam = (const int*)d_in[1];
    const float* Wih = (const float*)d_in[2];
    const float* Whh = (const float*)d_in[3];
    const float* bih = (const float*)d_in[4];
    const float* bhh = (const float*)d_in[5];
    const float* Wc  = (const float*)d_in[6];
    const float* bc  = (const float*)d_in[7];
    float* outp = (float*)d_out;

    char* w = (char*)d_ws;
    int* order = (int*)w; w += B_ * 4;
    int* tcam  = (int*)w; w += MAXT * 4;
    int* toff  = (int*)w; w += MAXT * 4;
    int* tcnt  = (int*)w; w += MAXT * 4;
    float* gi  = (float*)w; w += (size_t)B_ * G3H_ * 4;
    float* h0  = (float*)w; w += (size_t)B_ * H_ * 4;
    float* h1  = (float*)w;

    sort_kernel<<<1, 256, 0, stream>>>(cam, order, tcam, toff, tcnt);
    hipMemsetAsync(h0, 0, (size_t)B_ * H_ * sizeof(float), stream);
    gi_kernel<<<dim3(MAXT, 4), 256, 0, stream>>>(x, Wih, bih, bhh, order, tcam, toff, tcnt, gi);

    float* hp[2] = { h0, h1 };
    for (int s = 0; s < T_; ++s) {
        step_kernel<<<dim3(MAXT, 6), 256, 0, stream>>>(
            Whh, bhh, gi, Wc, bc, order, tcam, toff, tcnt,
            hp[s & 1], hp[(s + 1) & 1], outp, s);
    }
    outlast_kernel<<<dim3(MAXT, 2), 256, 0, stream>>>(Wc, bc, order, tcam, toff, tcnt,
                                                      hp[0], outp);
}